// Round 3
// baseline (369.190 us; speedup 1.0000x reference)
//
#include <hip/hip_runtime.h>
#include <hip/hip_bf16.h>

// ---------------- problem constants ----------------
constexpr int Bc = 32, Sc = 4096, Ic = 64, Hc = 512, Oc = 64;
constexpr int Lc = 128;            // chunk length (timesteps per block)
constexpr int NCc = Sc / Lc;       // 32 chunks
constexpr int HSUB = 128;          // h-subtile width
constexpr int NSUB = Hc / HSUB;    // 4 subtiles

typedef __attribute__((ext_vector_type(8))) short short8;
typedef __attribute__((ext_vector_type(4))) float float4v;

__device__ __forceinline__ short f2bf(float f) {
    unsigned u = __builtin_bit_cast(unsigned, f);
    u += 0x7FFFu + ((u >> 16) & 1u);   // RNE
    return (short)(u >> 16);
}

// XOR-swizzle for the h tile (row-major [128][256B]) — kills the 16-way bank
// conflict on MFMA-fragment column reads (G4 rule). Same function on write & read.
__device__ __forceinline__ int swz(int row, int rowBytes, int byteInRow) {
    return row * rowBytes + (byteInRow ^ ((row & 7) << 4));
}

// ---------------- K0: transpose/convert weights ----------------
// bT[h][i] bf16 (512x64), cT[o][h] bf16 (64x512)
__global__ void prep_kernel(const float* __restrict__ bw, const float* __restrict__ cw,
                            short* __restrict__ bT, short* __restrict__ cT) {
    int gid = blockIdx.x * 256 + threadIdx.x;   // 65536 total
    if (gid < Ic * Hc) {
        int i = gid / Hc, h = gid % Hc;         // coalesced read over h
        bT[h * Ic + i] = f2bf(bw[gid]);
    } else {
        int idx = gid - Ic * Hc;                // c is [H][O]
        int h = idx / Oc, o = idx % Oc;
        cT[o * Hc + h] = f2bf(cw[idx]);
    }
}

// ---------------- K2: combine chunk carries ----------------
__global__ void carry_kernel(const float* __restrict__ Adiag, const float* __restrict__ last,
                             float* __restrict__ carryIn) {
    int gid = blockIdx.x * 256 + threadIdx.x;   // 16384 = B*H
    int b = gid >> 9, h = gid & (Hc - 1);
    float a = Adiag[h];
    float aL = a;                               // a^128 via 7 squarings
#pragma unroll
    for (int i = 0; i < 7; i++) aL *= aL;
    float run = 0.f;
    for (int k = 0; k < NCc; k++) {
        size_t idx = ((size_t)b * NCc + k) * Hc + h;
        carryIn[idx] = run;
        run = fmaf(aL, run, last[idx]);
    }
}

// ---------------- K1/K3: per-chunk fused kernel ----------------
// WRITE_Y=0: zero-init local scan aggregates only -> lastOut.
// WRITE_Y=1: full scan seeded with carryIn, fused y = h @ c -> out.
template <int WRITE_Y>
__global__ __launch_bounds__(256, WRITE_Y ? 3 : 4) void chunk_kernel(
    const float* __restrict__ x, const short* __restrict__ bT,
    const short* __restrict__ cT, const float* __restrict__ Adiag,
    const float* __restrict__ carryIn, float* __restrict__ lastOut,
    float* __restrict__ out) {
    extern __shared__ char smem[];
    char* hbuf = smem;                                   // K3: [128][256B] swizzled bf16, 32 KB
    float* agg = (float*)(smem + (WRITE_Y ? 32768 : 0)); // [2][4 waves][128 cols] f32, 4 KB

    const int tid = threadIdx.x;
    const int chunk = blockIdx.x, b = blockIdx.y;
    const int t0 = chunk * Lc;
    const int l = tid & 63;
    const int wid = tid >> 6;      // wave id 0..3
    const int tg = wid * 32;       // wave's 32-row t-slice
    const int lr = l & 15;
    const int g = l >> 4;          // lane group = k-slice = t-subgroup

    // ---- X fragments: direct global f32 -> bf16, once per block ----
    short8 xf[2][2];
#pragma unroll
    for (int ti = 0; ti < 2; ti++) {
        const float* xr = x + ((size_t)b * Sc + t0 + tg + ti * 16 + lr) * Ic + g * 8;
#pragma unroll
        for (int ks = 0; ks < 2; ks++) {
            float4v v0 = *(const float4v*)(xr + ks * 32);
            float4v v1 = *(const float4v*)(xr + ks * 32 + 4);
            short8 f;
            f[0] = f2bf(v0[0]); f[1] = f2bf(v0[1]); f[2] = f2bf(v0[2]); f[3] = f2bf(v0[3]);
            f[4] = f2bf(v1[0]); f[5] = f2bf(v1[1]); f[6] = f2bf(v1[2]); f[7] = f2bf(v1[3]);
            xf[ti][ks] = f;
        }
    }

    float4v yacc[2][4];
    if (WRITE_Y) {
#pragma unroll
        for (int i = 0; i < 2; i++)
#pragma unroll
            for (int j = 0; j < 4; j++) yacc[i][j] = (float4v)0.f;
    }

#pragma unroll 1
    for (int hsu = 0; hsu < NSUB; hsu++) {
        const int buf = hsu & 1;
        float4v acc[2][8];   // [ti][hj]: xb, then wave-local inclusive scan values

        // ---- xb = X @ b (b-fragments straight from global, L2-resident) ----
#pragma unroll
        for (int hj = 0; hj < 8; hj++) {
            const short* br = bT + ((hsu * HSUB + hj * 16 + lr) * Ic + g * 8);
            short8 b0 = *(const short8*)br;
            short8 b1 = *(const short8*)(br + 32);
#pragma unroll
            for (int ti = 0; ti < 2; ti++) {
                float4v t = (float4v)0.f;
                t = __builtin_amdgcn_mfma_f32_16x16x32_bf16(xf[ti][0], b0, t, 0, 0, 0);
                t = __builtin_amdgcn_mfma_f32_16x16x32_bf16(xf[ti][1], b1, t, 0, 0, 0);
                acc[ti][hj] = t;
            }
        }

        // ---- in-register zero-init scan over the wave's 32 t-steps ----
        // lane holds t = tg + ti*16 + 4g + r ; column = hj*16 + lr
#pragma unroll
        for (int hj = 0; hj < 8; hj++) {
            float a = Adiag[hsu * HSUB + hj * 16 + lr];
            float a2 = a * a, a3 = a2 * a, a4 = a2 * a2, a8 = a4 * a4, a16 = a8 * a8;
            float a4g = ((g & 1) ? a4 : 1.f) * ((g & 2) ? a8 : 1.f);   // a^(4g)
            // lane-local 4-step inclusive scan (both ti)
#pragma unroll
            for (int ti = 0; ti < 2; ti++) {
                acc[ti][hj][1] = fmaf(acc[ti][hj][0], a, acc[ti][hj][1]);
                acc[ti][hj][2] = fmaf(acc[ti][hj][1], a, acc[ti][hj][2]);
                acc[ti][hj][3] = fmaf(acc[ti][hj][2], a, acc[ti][hj][3]);
            }
            // Hillis-Steele across the 4 lane-groups (stride 16), multiplier a^4 then a^8
            float s0 = acc[0][hj][3];
            float u = __shfl_up(s0, 16u, 64); s0 = (g >= 1) ? fmaf(u, a4, s0) : s0;
            u = __shfl_up(s0, 32u, 64);       s0 = (g >= 2) ? fmaf(u, a8, s0) : s0;
            float E0 = __shfl_up(s0, 16u, 64); E0 = (g >= 1) ? E0 : 0.f;   // exclusive prefix
            float S16_0 = __shfl(s0, lr + 48, 64);                          // ti0 16-total
            float s1 = acc[1][hj][3];
            u = __shfl_up(s1, 16u, 64); s1 = (g >= 1) ? fmaf(u, a4, s1) : s1;
            u = __shfl_up(s1, 32u, 64); s1 = (g >= 2) ? fmaf(u, a8, s1) : s1;
            float E1 = __shfl_up(s1, 16u, 64); E1 = (g >= 1) ? E1 : 0.f;
            E1 = fmaf(a4g, S16_0, E1);          // + ti0 total evolved into this group
            float S16_1 = __shfl(s1, lr + 48, 64);
            // correct lane-local values to wave-local inclusive
#pragma unroll
            for (int r = 0; r < 4; r++) {
                float apr = (r == 0) ? a : (r == 1) ? a2 : (r == 2) ? a3 : a4;
                acc[0][hj][r] = fmaf(apr, E0, acc[0][hj][r]);
                acc[1][hj][r] = fmaf(apr, E1, acc[1][hj][r]);
            }
            float S32 = fmaf(a16, S16_0, S16_1);   // wave 32-step total
            if (l < 16) agg[(buf * 4 + wid) * 128 + hj * 16 + l] = S32;
        }
        __syncthreads();   // the ONLY barrier per subtile (agg double-buffered)

        if (WRITE_Y) {
            // ---- cross-wave prefix + chunk carry, correct, store h (bf16) ----
#pragma unroll
            for (int hj = 0; hj < 8; hj++) {
                float a = Adiag[hsu * HSUB + hj * 16 + lr];
                float a2 = a * a, a3 = a2 * a, a4 = a2 * a2, a8 = a4 * a4;
                float a16 = a8 * a8, a32 = a16 * a16;
                float a4g = ((g & 1) ? a4 : 1.f) * ((g & 2) ? a8 : 1.f);
                float P = carryIn[((size_t)b * NCc + chunk) * Hc + hsu * HSUB + hj * 16 + lr];
                for (int j = 0; j < wid; j++)
                    P = fmaf(P, a32, agg[(buf * 4 + j) * 128 + hj * 16 + lr]);
                float base0 = P * a4g;       // prefix evolved to this lane-group, ti0
                float base1 = base0 * a16;   // ti1
#pragma unroll
                for (int ti = 0; ti < 2; ti++) {
                    float bb = ti ? base1 : base0;
#pragma unroll
                    for (int r = 0; r < 4; r++) {
                        float apr = (r == 0) ? a : (r == 1) ? a2 : (r == 2) ? a3 : a4;
                        float hv = fmaf(apr, bb, acc[ti][hj][r]);
                        int trow = tg + ti * 16 + g * 4 + r;
                        *(short*)(hbuf + swz(trow, 256, (hj * 16 + lr) * 2)) = f2bf(hv);
                    }
                }
            }
            // ---- y += h @ c (A-frags: own rows of hbuf; B-frags: global cT) ----
#pragma unroll
            for (int ks = 0; ks < 4; ks++) {
                short8 af[2];
#pragma unroll
                for (int ti = 0; ti < 2; ti++)
                    af[ti] = *(const short8*)(hbuf + swz(tg + ti * 16 + lr, 256, ks * 64 + g * 16));
#pragma unroll
                for (int oj = 0; oj < 4; oj++) {
                    const short* cr = cT + (oj * 16 + lr) * Hc + hsu * HSUB + ks * 32 + g * 8;
                    short8 bf = *(const short8*)cr;
#pragma unroll
                    for (int ti = 0; ti < 2; ti++)
                        yacc[ti][oj] = __builtin_amdgcn_mfma_f32_16x16x32_bf16(af[ti], bf, yacc[ti][oj], 0, 0, 0);
                }
            }
        } else {
            // ---- K1: combine the 4 wave aggregates -> chunk total -> lastOut ----
            if (tid < HSUB) {
                int h = hsu * HSUB + tid;
                float a = Adiag[h];
                float a2 = a * a, a4 = a2 * a2, a8 = a4 * a4;
                float a16 = a8 * a8, a32 = a16 * a16;
                float W = agg[(buf * 4 + 0) * 128 + tid];
                W = fmaf(W, a32, agg[(buf * 4 + 1) * 128 + tid]);
                W = fmaf(W, a32, agg[(buf * 4 + 2) * 128 + tid]);
                W = fmaf(W, a32, agg[(buf * 4 + 3) * 128 + tid]);
                lastOut[((size_t)b * NCc + chunk) * Hc + h] = W;
            }
        }
    }

    // ---- write y tile ----
    if (WRITE_Y) {
        float* og = out + ((size_t)b * Sc + t0) * Oc;
#pragma unroll
        for (int ti = 0; ti < 2; ti++)
#pragma unroll
            for (int oj = 0; oj < 4; oj++)
#pragma unroll
                for (int r = 0; r < 4; r++) {
                    int t = tg + ti * 16 + g * 4 + r;
                    int o = oj * 16 + lr;
                    og[t * Oc + o] = yacc[ti][oj][r];
                }
    }
}

// ---------------- host launch ----------------
extern "C" void kernel_launch(void* const* d_in, const int* in_sizes, int n_in,
                              void* d_out, int out_size, void* d_ws, size_t ws_size,
                              hipStream_t stream) {
    (void)in_sizes; (void)n_in; (void)out_size; (void)ws_size;
    const float* x     = (const float*)d_in[0];   // [B,S,I] f32
    const float* bw    = (const float*)d_in[1];   // [I,H]   f32
    const float* Adiag = (const float*)d_in[2];   // [H]     f32
    const float* cw    = (const float*)d_in[3];   // [H,O]   f32
    float* out = (float*)d_out;                   // [B,S*O] f32

    float* last    = (float*)d_ws;                               // [B][NC][H] f32, 2 MB
    float* carryIn = last + (size_t)Bc * NCc * Hc;               // [B][NC][H] f32, 2 MB
    short* bT      = (short*)(carryIn + (size_t)Bc * NCc * Hc);  // [H][I] bf16, 64 KB
    short* cT      = bT + Ic * Hc;                               // [O][H] bf16, 64 KB

    prep_kernel<<<256, 256, 0, stream>>>(bw, cw, bT, cT);
    chunk_kernel<0><<<dim3(NCc, Bc), 256, 4096, stream>>>(x, bT, cT, Adiag, nullptr, last, nullptr);
    carry_kernel<<<64, 256, 0, stream>>>(Adiag, last, carryIn);
    chunk_kernel<1><<<dim3(NCc, Bc), 256, 36864, stream>>>(x, bT, cT, Adiag, carryIn, nullptr, out);
}

// Round 4
// 235.368 us; speedup vs baseline: 1.5686x; 1.5686x over previous
//
#include <hip/hip_runtime.h>
#include <hip/hip_bf16.h>

// ---------------- problem constants ----------------
constexpr int Bc = 32, Sc = 4096, Ic = 64, Hc = 512, Oc = 64;
constexpr int Lc = 128;            // chunk length (timesteps per block)
constexpr int NCc = Sc / Lc;       // 32 chunks
constexpr int HSUB = 128;          // h-subtile width
constexpr int NSUB = Hc / HSUB;    // 4 subtiles

typedef __attribute__((ext_vector_type(8))) short short8;
typedef __attribute__((ext_vector_type(4))) float float4v;

__device__ __forceinline__ short f2bf(float f) {
    unsigned u = __builtin_bit_cast(unsigned, f);
    u += 0x7FFFu + ((u >> 16) & 1u);   // RNE
    return (short)(u >> 16);
}

// XOR-swizzle for the h tile (row-major [128][256B]) — kills the 16-way bank
// conflict on MFMA-fragment column reads (G4 rule). Same function on write & read.
__device__ __forceinline__ int swz(int row, int rowBytes, int byteInRow) {
    return row * rowBytes + (byteInRow ^ ((row & 7) << 4));
}

// ---------------- K0: transpose/convert weights ----------------
// bT[h][i] bf16 (512x64), cT[o][h] bf16 (64x512)
__global__ void prep_kernel(const float* __restrict__ bw, const float* __restrict__ cw,
                            short* __restrict__ bT, short* __restrict__ cT) {
    int gid = blockIdx.x * 256 + threadIdx.x;   // 65536 total
    if (gid < Ic * Hc) {
        int i = gid / Hc, h = gid % Hc;         // coalesced read over h
        bT[h * Ic + i] = f2bf(bw[gid]);
    } else {
        int idx = gid - Ic * Hc;                // c is [H][O]
        int h = idx / Oc, o = idx % Oc;
        cT[o * Hc + h] = f2bf(cw[idx]);
    }
}

// ---------------- K2: combine chunk carries ----------------
__global__ void carry_kernel(const float* __restrict__ Adiag, const float* __restrict__ last,
                             float* __restrict__ carryIn) {
    int gid = blockIdx.x * 256 + threadIdx.x;   // 16384 = B*H
    int b = gid >> 9, h = gid & (Hc - 1);
    float a = Adiag[h];
    float aL = a;                               // a^128 via 7 squarings
#pragma unroll
    for (int i = 0; i < 7; i++) aL *= aL;
    float run = 0.f;
    for (int k = 0; k < NCc; k++) {
        size_t idx = ((size_t)b * NCc + k) * Hc + h;
        carryIn[idx] = run;
        run = fmaf(aL, run, last[idx]);
    }
}

// ---------------- K1/K3: per-chunk fused kernel ----------------
// WRITE_Y=0: zero-init local scan aggregates only -> lastOut.
// WRITE_Y=1: full scan seeded with carryIn, fused y = h @ c -> out.
// NOTE: __launch_bounds__(256, 2): the MFMA accumulators live in the unified
// VGPR/AGPR file; acc(64)+yacc(32)+xf(16)+temps ~ 200 regs. A min-waves of 3+
// caps the file at ~170 and forces scratch spills (R3: 84 VGPR + ~400 MB
// scratch traffic, 263 us/dispatch). 2 waves/EU -> cap 256, no spill.
template <int WRITE_Y>
__global__ __launch_bounds__(256, 2) void chunk_kernel(
    const float* __restrict__ x, const short* __restrict__ bT,
    const short* __restrict__ cT, const float* __restrict__ Adiag,
    const float* __restrict__ carryIn, float* __restrict__ lastOut,
    float* __restrict__ out) {
    extern __shared__ char smem[];
    char* hbuf = smem;                                   // K3: [128][256B] swizzled bf16, 32 KB
    float* agg = (float*)(smem + (WRITE_Y ? 32768 : 0)); // [2][4 waves][128 cols] f32, 4 KB

    const int tid = threadIdx.x;
    const int chunk = blockIdx.x, b = blockIdx.y;
    const int t0 = chunk * Lc;
    const int l = tid & 63;
    const int wid = tid >> 6;      // wave id 0..3
    const int tg = wid * 32;       // wave's 32-row t-slice
    const int lr = l & 15;
    const int g = l >> 4;          // lane group = k-slice = t-subgroup

    // ---- X fragments: direct global f32 -> bf16, once per block ----
    short8 xf[2][2];
#pragma unroll
    for (int ti = 0; ti < 2; ti++) {
        const float* xr = x + ((size_t)b * Sc + t0 + tg + ti * 16 + lr) * Ic + g * 8;
#pragma unroll
        for (int ks = 0; ks < 2; ks++) {
            float4v v0 = *(const float4v*)(xr + ks * 32);
            float4v v1 = *(const float4v*)(xr + ks * 32 + 4);
            short8 f;
            f[0] = f2bf(v0[0]); f[1] = f2bf(v0[1]); f[2] = f2bf(v0[2]); f[3] = f2bf(v0[3]);
            f[4] = f2bf(v1[0]); f[5] = f2bf(v1[1]); f[6] = f2bf(v1[2]); f[7] = f2bf(v1[3]);
            xf[ti][ks] = f;
        }
    }

    float4v yacc[2][4];
    if (WRITE_Y) {
#pragma unroll
        for (int i = 0; i < 2; i++)
#pragma unroll
            for (int j = 0; j < 4; j++) yacc[i][j] = (float4v)0.f;
    }

#pragma unroll 1
    for (int hsu = 0; hsu < NSUB; hsu++) {
        const int buf = hsu & 1;
        float4v acc[2][8];   // [ti][hj]: xb, then wave-local inclusive scan values

        // ---- xb = X @ b (b-fragments straight from global, L2-resident) ----
#pragma unroll
        for (int hj = 0; hj < 8; hj++) {
            const short* br = bT + ((hsu * HSUB + hj * 16 + lr) * Ic + g * 8);
            short8 b0 = *(const short8*)br;
            short8 b1 = *(const short8*)(br + 32);
#pragma unroll
            for (int ti = 0; ti < 2; ti++) {
                float4v t = (float4v)0.f;
                t = __builtin_amdgcn_mfma_f32_16x16x32_bf16(xf[ti][0], b0, t, 0, 0, 0);
                t = __builtin_amdgcn_mfma_f32_16x16x32_bf16(xf[ti][1], b1, t, 0, 0, 0);
                acc[ti][hj] = t;
            }
        }

        // ---- in-register zero-init scan over the wave's 32 t-steps ----
        // lane holds t = tg + ti*16 + 4g + r ; column = hj*16 + lr
#pragma unroll
        for (int hj = 0; hj < 8; hj++) {
            float a = Adiag[hsu * HSUB + hj * 16 + lr];
            float a2 = a * a, a3 = a2 * a, a4 = a2 * a2, a8 = a4 * a4, a16 = a8 * a8;
            float a4g = ((g & 1) ? a4 : 1.f) * ((g & 2) ? a8 : 1.f);   // a^(4g)
            // lane-local 4-step inclusive scan (both ti)
#pragma unroll
            for (int ti = 0; ti < 2; ti++) {
                acc[ti][hj][1] = fmaf(acc[ti][hj][0], a, acc[ti][hj][1]);
                acc[ti][hj][2] = fmaf(acc[ti][hj][1], a, acc[ti][hj][2]);
                acc[ti][hj][3] = fmaf(acc[ti][hj][2], a, acc[ti][hj][3]);
            }
            // Hillis-Steele across the 4 lane-groups (stride 16), multiplier a^4 then a^8
            float s0 = acc[0][hj][3];
            float u = __shfl_up(s0, 16u, 64); s0 = (g >= 1) ? fmaf(u, a4, s0) : s0;
            u = __shfl_up(s0, 32u, 64);       s0 = (g >= 2) ? fmaf(u, a8, s0) : s0;
            float E0 = __shfl_up(s0, 16u, 64); E0 = (g >= 1) ? E0 : 0.f;   // exclusive prefix
            float S16_0 = __shfl(s0, lr + 48, 64);                          // ti0 16-total
            float s1 = acc[1][hj][3];
            u = __shfl_up(s1, 16u, 64); s1 = (g >= 1) ? fmaf(u, a4, s1) : s1;
            u = __shfl_up(s1, 32u, 64); s1 = (g >= 2) ? fmaf(u, a8, s1) : s1;
            float E1 = __shfl_up(s1, 16u, 64); E1 = (g >= 1) ? E1 : 0.f;
            E1 = fmaf(a4g, S16_0, E1);          // + ti0 total evolved into this group
            float S16_1 = __shfl(s1, lr + 48, 64);
            // correct lane-local values to wave-local inclusive
#pragma unroll
            for (int r = 0; r < 4; r++) {
                float apr = (r == 0) ? a : (r == 1) ? a2 : (r == 2) ? a3 : a4;
                acc[0][hj][r] = fmaf(apr, E0, acc[0][hj][r]);
                acc[1][hj][r] = fmaf(apr, E1, acc[1][hj][r]);
            }
            float S32 = fmaf(a16, S16_0, S16_1);   // wave 32-step total
            if (l < 16) agg[(buf * 4 + wid) * 128 + hj * 16 + l] = S32;
            // pressure fence: keep at most 2 hj shuffle-chains in flight so the
            // scheduler doesn't interleave all 8 and blow the register budget
            if (hj & 1) __builtin_amdgcn_sched_barrier(0);
        }
        __syncthreads();   // the ONLY barrier per subtile (agg double-buffered)

        if (WRITE_Y) {
            // ---- cross-wave prefix + chunk carry, correct, store h (bf16) ----
#pragma unroll
            for (int hj = 0; hj < 8; hj++) {
                float a = Adiag[hsu * HSUB + hj * 16 + lr];
                float a2 = a * a, a3 = a2 * a, a4 = a2 * a2, a8 = a4 * a4;
                float a16 = a8 * a8, a32 = a16 * a16;
                float a4g = ((g & 1) ? a4 : 1.f) * ((g & 2) ? a8 : 1.f);
                float P = carryIn[((size_t)b * NCc + chunk) * Hc + hsu * HSUB + hj * 16 + lr];
                for (int j = 0; j < wid; j++)
                    P = fmaf(P, a32, agg[(buf * 4 + j) * 128 + hj * 16 + lr]);
                float base0 = P * a4g;       // prefix evolved to this lane-group, ti0
                float base1 = base0 * a16;   // ti1
#pragma unroll
                for (int ti = 0; ti < 2; ti++) {
                    float bb = ti ? base1 : base0;
#pragma unroll
                    for (int r = 0; r < 4; r++) {
                        float apr = (r == 0) ? a : (r == 1) ? a2 : (r == 2) ? a3 : a4;
                        float hv = fmaf(apr, bb, acc[ti][hj][r]);
                        int trow = tg + ti * 16 + g * 4 + r;
                        *(short*)(hbuf + swz(trow, 256, (hj * 16 + lr) * 2)) = f2bf(hv);
                    }
                }
            }
            // ---- y += h @ c (A-frags: own rows of hbuf; B-frags: global cT) ----
#pragma unroll
            for (int ks = 0; ks < 4; ks++) {
                short8 af[2];
#pragma unroll
                for (int ti = 0; ti < 2; ti++)
                    af[ti] = *(const short8*)(hbuf + swz(tg + ti * 16 + lr, 256, ks * 64 + g * 16));
#pragma unroll
                for (int oj = 0; oj < 4; oj++) {
                    const short* cr = cT + (oj * 16 + lr) * Hc + hsu * HSUB + ks * 32 + g * 8;
                    short8 bf = *(const short8*)cr;
#pragma unroll
                    for (int ti = 0; ti < 2; ti++)
                        yacc[ti][oj] = __builtin_amdgcn_mfma_f32_16x16x32_bf16(af[ti], bf, yacc[ti][oj], 0, 0, 0);
                }
            }
        } else {
            // ---- K1: combine the 4 wave aggregates -> chunk total -> lastOut ----
            if (tid < HSUB) {
                int h = hsu * HSUB + tid;
                float a = Adiag[h];
                float a2 = a * a, a4 = a2 * a2, a8 = a4 * a4;
                float a16 = a8 * a8, a32 = a16 * a16;
                float W = agg[(buf * 4 + 0) * 128 + tid];
                W = fmaf(W, a32, agg[(buf * 4 + 1) * 128 + tid]);
                W = fmaf(W, a32, agg[(buf * 4 + 2) * 128 + tid]);
                W = fmaf(W, a32, agg[(buf * 4 + 3) * 128 + tid]);
                lastOut[((size_t)b * NCc + chunk) * Hc + h] = W;
            }
        }
    }

    // ---- write y tile ----
    if (WRITE_Y) {
        float* og = out + ((size_t)b * Sc + t0) * Oc;
#pragma unroll
        for (int ti = 0; ti < 2; ti++)
#pragma unroll
            for (int oj = 0; oj < 4; oj++)
#pragma unroll
                for (int r = 0; r < 4; r++) {
                    int t = tg + ti * 16 + g * 4 + r;
                    int o = oj * 16 + lr;
                    og[t * Oc + o] = yacc[ti][oj][r];
                }
    }
}

// ---------------- host launch ----------------
extern "C" void kernel_launch(void* const* d_in, const int* in_sizes, int n_in,
                              void* d_out, int out_size, void* d_ws, size_t ws_size,
                              hipStream_t stream) {
    (void)in_sizes; (void)n_in; (void)out_size; (void)ws_size;
    const float* x     = (const float*)d_in[0];   // [B,S,I] f32
    const float* bw    = (const float*)d_in[1];   // [I,H]   f32
    const float* Adiag = (const float*)d_in[2];   // [H]     f32
    const float* cw    = (const float*)d_in[3];   // [H,O]   f32
    float* out = (float*)d_out;                   // [B,S*O] f32

    float* last    = (float*)d_ws;                               // [B][NC][H] f32, 2 MB
    float* carryIn = last + (size_t)Bc * NCc * Hc;               // [B][NC][H] f32, 2 MB
    short* bT      = (short*)(carryIn + (size_t)Bc * NCc * Hc);  // [H][I] bf16, 64 KB
    short* cT      = bT + Ic * Hc;                               // [O][H] bf16, 64 KB

    prep_kernel<<<256, 256, 0, stream>>>(bw, cw, bT, cT);
    chunk_kernel<0><<<dim3(NCc, Bc), 256, 4096, stream>>>(x, bT, cT, Adiag, nullptr, last, nullptr);
    carry_kernel<<<64, 256, 0, stream>>>(Adiag, last, carryIn);
    chunk_kernel<1><<<dim3(NCc, Bc), 256, 36864, stream>>>(x, bT, cT, Adiag, carryIn, nullptr, out);
}

// Round 5
// 184.674 us; speedup vs baseline: 1.9991x; 1.2745x over previous
//
#include <hip/hip_runtime.h>
#include <hip/hip_bf16.h>

// ---------------- problem constants ----------------
constexpr int Bc = 32, Sc = 4096, Ic = 64, Hc = 512, Oc = 64;
constexpr int Lc = 128;            // chunk length (timesteps per block)
constexpr int NCc = Sc / Lc;       // 32 chunks
constexpr int HSUB = 128;          // h-subtile width
constexpr int NSUB = Hc / HSUB;    // 4 subtiles
constexpr int WPB = 4;             // waves per block

typedef __attribute__((ext_vector_type(8))) short short8;
typedef __attribute__((ext_vector_type(4))) float float4v;

__device__ __forceinline__ short f2bf(float f) {
    unsigned u = __builtin_bit_cast(unsigned, f);
    u += 0x7FFFu + ((u >> 16) & 1u);   // RNE
    return (short)(u >> 16);
}

// XOR-swizzle for the LDS h tile (row-major [128][256B]) — kills the 16-way
// bank conflict on MFMA-fragment column reads. Same function on write & read.
__device__ __forceinline__ int swz(int row, int rowBytes, int byteInRow) {
    return row * rowBytes + (byteInRow ^ ((row & 7) << 4));
}

// ---------------- K0: weights -> MFMA-fragment-ordered bf16 ----------------
// bfrag slot s = ((hsu*8+hj)*2+ks)*64 + l : lane l's short8 for that B-frag.
// cfrag slot s = ((hsu*4+ks)*4+oj)*64 + l.
// In the chunk kernels these become perfectly coalesced 1KB wave loads.
__global__ void prep_weights(const float* __restrict__ bw, const float* __restrict__ cw,
                             short* __restrict__ bfrag, short* __restrict__ cfrag) {
    int s = blockIdx.x * 256 + threadIdx.x;   // 8192 total
    int l = s & 63, g = (l >> 4), lr = l & 15;
    if (s < 4096) {
        int ks = (s >> 6) & 1, hj = (s >> 7) & 7, hsu = (s >> 10) & 3;
        short8 v;
#pragma unroll
        for (int j = 0; j < 8; j++)
            v[j] = f2bf(bw[(ks * 32 + g * 8 + j) * Hc + hsu * HSUB + hj * 16 + lr]);
        *(short8*)(bfrag + (size_t)s * 8) = v;
    } else {
        int idx = s - 4096;
        int oj = (idx >> 6) & 3, ks = (idx >> 8) & 3, hsu = (idx >> 10) & 3;
        short8 v;
#pragma unroll
        for (int j = 0; j < 8; j++)
            v[j] = f2bf(cw[(hsu * HSUB + ks * 32 + g * 8 + j) * Oc + oj * 16 + lr]);
        *(short8*)(cfrag + (size_t)idx * 8) = v;
    }
}

// ---------------- shared helper: per-lane X fragments (direct global) -------
// lane holds x[t = t0 + tg + ti*16 + lr][k = ks*32 + g*8 .. +8] as bf16.
__device__ __forceinline__ void load_xfrag(const float* __restrict__ x, int b, int t0,
                                           int tg, int lr, int g, short8 xf[2][2]) {
#pragma unroll
    for (int ti = 0; ti < 2; ti++) {
        const float* xr = x + ((size_t)b * Sc + t0 + tg + ti * 16 + lr) * Ic + g * 8;
#pragma unroll
        for (int ks = 0; ks < 2; ks++) {
            float4v v0 = *(const float4v*)(xr + ks * 32);
            float4v v1 = *(const float4v*)(xr + ks * 32 + 4);
            short8 f;
            f[0] = f2bf(v0[0]); f[1] = f2bf(v0[1]); f[2] = f2bf(v0[2]); f[3] = f2bf(v0[3]);
            f[4] = f2bf(v1[0]); f[5] = f2bf(v1[1]); f[6] = f2bf(v1[2]); f[7] = f2bf(v1[3]);
            xf[ti][ks] = f;
        }
    }
}

// ---------------- K1: per-wave 32-step aggregates only ----------------------
// No LDS, no barriers. wlast[b][chunk][wave][h] = zero-init 32-step total.
__global__ __launch_bounds__(256, 4) void pass1(
    const float* __restrict__ x, const short* __restrict__ bfrag,
    const float* __restrict__ Adiag, float* __restrict__ wlast) {
    const int tid = threadIdx.x;
    const int chunk = blockIdx.x, b = blockIdx.y;
    const int t0 = chunk * Lc;
    const int l = tid & 63, wid = tid >> 6, tg = wid * 32;
    const int lr = l & 15, g = l >> 4;

    short8 xf[2][2];
    load_xfrag(x, b, t0, tg, lr, g, xf);

    float* wl = wlast + ((size_t)(b * NCc + chunk) * WPB + wid) * Hc;

#pragma unroll 1
    for (int hsu = 0; hsu < NSUB; hsu++) {
#pragma unroll
        for (int hj = 0; hj < 8; hj++) {
            const short8* bf = (const short8*)bfrag + ((hsu * 8 + hj) * 2) * 64 + l;
            short8 b0 = bf[0];
            short8 b1 = bf[64];
            float4v a0 = (float4v)0.f, a1 = (float4v)0.f;
            a0 = __builtin_amdgcn_mfma_f32_16x16x32_bf16(xf[0][0], b0, a0, 0, 0, 0);
            a0 = __builtin_amdgcn_mfma_f32_16x16x32_bf16(xf[0][1], b1, a0, 0, 0, 0);
            a1 = __builtin_amdgcn_mfma_f32_16x16x32_bf16(xf[1][0], b0, a1, 0, 0, 0);
            a1 = __builtin_amdgcn_mfma_f32_16x16x32_bf16(xf[1][1], b1, a1, 0, 0, 0);

            float a = Adiag[hsu * HSUB + hj * 16 + lr];
            float a2 = a * a, a4 = a2 * a2, a8 = a4 * a4, a16 = a8 * a8;
            // lane-local 4-step totals (inclusive last element)
            float s0 = fmaf(fmaf(fmaf(a0[0], a, a0[1]), a, a0[2]), a, a0[3]);
            float s1 = fmaf(fmaf(fmaf(a1[0], a, a1[1]), a, a1[2]), a, a1[3]);
            // Hillis-Steele across the 4 lane-groups (stride 16)
            float u = __shfl_up(s0, 16u, 64); s0 = (g >= 1) ? fmaf(u, a4, s0) : s0;
            u = __shfl_up(s0, 32u, 64);       s0 = (g >= 2) ? fmaf(u, a8, s0) : s0;
            float S16_0 = __shfl(s0, lr + 48, 64);
            u = __shfl_up(s1, 16u, 64); s1 = (g >= 1) ? fmaf(u, a4, s1) : s1;
            u = __shfl_up(s1, 32u, 64); s1 = (g >= 2) ? fmaf(u, a8, s1) : s1;
            float S16_1 = __shfl(s1, lr + 48, 64);
            float S32 = fmaf(a16, S16_0, S16_1);
            if (l < 16) wl[hsu * HSUB + hj * 16 + l] = S32;
            if (hj & 1) __builtin_amdgcn_sched_barrier(0);
        }
    }
}

// ---------------- K2: in-place wlast -> per-wave carry ----------------------
// After this, wlast[b][k][w][h] = true h-state entering wave w of chunk k.
__global__ void carry2(const float* __restrict__ Adiag, float* __restrict__ wl) {
    int gid = blockIdx.x * 256 + threadIdx.x;   // 16384 = B*H
    int b = gid >> 9, h = gid & (Hc - 1);
    float a = Adiag[h];
    float a32 = a;
#pragma unroll
    for (int i = 0; i < 5; i++) a32 *= a32;     // a^32
    float run = 0.f;
#pragma unroll 4
    for (int kw = 0; kw < NCc * WPB; kw++) {
        size_t idx = ((size_t)b * NCc * WPB + kw) * Hc + h;
        float tmp = wl[idx];
        wl[idx] = run;
        run = fmaf(a32, run, tmp);
    }
}

// ---------------- K3: full scan + fused y = h @ c ---------------------------
// Zero barriers: carry comes per-wave from carryW; h tile is own-wave LDS.
__global__ __launch_bounds__(256, 3) void pass2(
    const float* __restrict__ x, const short* __restrict__ bfrag,
    const short* __restrict__ cfrag, const float* __restrict__ Adiag,
    const float* __restrict__ carryW, float* __restrict__ out) {
    __shared__ char hbuf[128 * 256];   // [t][h-sub] bf16, swizzled, 32 KB

    const int tid = threadIdx.x;
    const int chunk = blockIdx.x, b = blockIdx.y;
    const int t0 = chunk * Lc;
    const int l = tid & 63, wid = tid >> 6, tg = wid * 32;
    const int lr = l & 15, g = l >> 4;

    short8 xf[2][2];
    load_xfrag(x, b, t0, tg, lr, g, xf);

    const float* cw0 = carryW + ((size_t)(b * NCc + chunk) * WPB + wid) * Hc;

    float4v yacc[2][4];
#pragma unroll
    for (int i = 0; i < 2; i++)
#pragma unroll
        for (int j = 0; j < 4; j++) yacc[i][j] = (float4v)0.f;

#pragma unroll 1
    for (int hsu = 0; hsu < NSUB; hsu++) {
#pragma unroll
        for (int hj = 0; hj < 8; hj++) {
            const short8* bfp = (const short8*)bfrag + ((hsu * 8 + hj) * 2) * 64 + l;
            short8 b0 = bfp[0];
            short8 b1 = bfp[64];
            float4v a0 = (float4v)0.f, a1 = (float4v)0.f;
            a0 = __builtin_amdgcn_mfma_f32_16x16x32_bf16(xf[0][0], b0, a0, 0, 0, 0);
            a0 = __builtin_amdgcn_mfma_f32_16x16x32_bf16(xf[0][1], b1, a0, 0, 0, 0);
            a1 = __builtin_amdgcn_mfma_f32_16x16x32_bf16(xf[1][0], b0, a1, 0, 0, 0);
            a1 = __builtin_amdgcn_mfma_f32_16x16x32_bf16(xf[1][1], b1, a1, 0, 0, 0);

            float a = Adiag[hsu * HSUB + hj * 16 + lr];
            float a2 = a * a, a3 = a2 * a, a4 = a2 * a2, a8 = a4 * a4, a16 = a8 * a8;
            float a4g = ((g & 1) ? a4 : 1.f) * ((g & 2) ? a8 : 1.f);   // a^(4g)
            // lane-local inclusive 4-step scan
            a0[1] = fmaf(a0[0], a, a0[1]); a0[2] = fmaf(a0[1], a, a0[2]); a0[3] = fmaf(a0[2], a, a0[3]);
            a1[1] = fmaf(a1[0], a, a1[1]); a1[2] = fmaf(a1[1], a, a1[2]); a1[3] = fmaf(a1[2], a, a1[3]);
            // cross-group Hillis-Steele + exclusive prefixes
            float s0 = a0[3];
            float u = __shfl_up(s0, 16u, 64); s0 = (g >= 1) ? fmaf(u, a4, s0) : s0;
            u = __shfl_up(s0, 32u, 64);       s0 = (g >= 2) ? fmaf(u, a8, s0) : s0;
            float E0 = __shfl_up(s0, 16u, 64); E0 = (g >= 1) ? E0 : 0.f;
            float S16_0 = __shfl(s0, lr + 48, 64);
            float s1 = a1[3];
            u = __shfl_up(s1, 16u, 64); s1 = (g >= 1) ? fmaf(u, a4, s1) : s1;
            u = __shfl_up(s1, 32u, 64); s1 = (g >= 2) ? fmaf(u, a8, s1) : s1;
            float E1 = __shfl_up(s1, 16u, 64); E1 = (g >= 1) ? E1 : 0.f;
            E1 = fmaf(a4g, S16_0, E1);   // ti0 total evolved into this group
            // per-wave carry (true state entering this wave)
            float P = cw0[hsu * HSUB + hj * 16 + lr];
            float base0 = P * a4g;        // evolved to this lane-group, ti0
            float base1 = base0 * a16;    // ti1
            float c0 = E0 + base0, c1 = E1 + base1;
#pragma unroll
            for (int r = 0; r < 4; r++) {
                float apr = (r == 0) ? a : (r == 1) ? a2 : (r == 2) ? a3 : a4;
                float h0 = fmaf(apr, c0, a0[r]);
                float h1 = fmaf(apr, c1, a1[r]);
                int row0 = tg + g * 4 + r;
                *(short*)(hbuf + swz(row0, 256, (hj * 16 + lr) * 2)) = f2bf(h0);
                *(short*)(hbuf + swz(row0 + 16, 256, (hj * 16 + lr) * 2)) = f2bf(h1);
            }
            if (hj & 1) __builtin_amdgcn_sched_barrier(0);
        }

        // ---- y += h @ c ; A-frags from own-wave rows of hbuf (no barrier) ----
#pragma unroll
        for (int ks = 0; ks < 4; ks++) {
            short8 af0 = *(const short8*)(hbuf + swz(tg + lr, 256, ks * 64 + g * 16));
            short8 af1 = *(const short8*)(hbuf + swz(tg + 16 + lr, 256, ks * 64 + g * 16));
#pragma unroll
            for (int oj = 0; oj < 4; oj++) {
                short8 cf = *((const short8*)cfrag + ((hsu * 4 + ks) * 4 + oj) * 64 + l);
                yacc[0][oj] = __builtin_amdgcn_mfma_f32_16x16x32_bf16(af0, cf, yacc[0][oj], 0, 0, 0);
                yacc[1][oj] = __builtin_amdgcn_mfma_f32_16x16x32_bf16(af1, cf, yacc[1][oj], 0, 0, 0);
            }
        }
    }

    // ---- write y tile ----
    float* og = out + ((size_t)b * Sc + t0) * Oc;
#pragma unroll
    for (int ti = 0; ti < 2; ti++)
#pragma unroll
        for (int oj = 0; oj < 4; oj++)
#pragma unroll
            for (int r = 0; r < 4; r++) {
                int t = tg + ti * 16 + g * 4 + r;
                int o = oj * 16 + lr;
                og[t * Oc + o] = yacc[ti][oj][r];
            }
}

// ---------------- host launch ----------------
extern "C" void kernel_launch(void* const* d_in, const int* in_sizes, int n_in,
                              void* d_out, int out_size, void* d_ws, size_t ws_size,
                              hipStream_t stream) {
    (void)in_sizes; (void)n_in; (void)out_size; (void)ws_size;
    const float* x     = (const float*)d_in[0];   // [B,S,I] f32
    const float* bw    = (const float*)d_in[1];   // [I,H]   f32
    const float* Adiag = (const float*)d_in[2];   // [H]     f32
    const float* cw    = (const float*)d_in[3];   // [H,O]   f32
    float* out = (float*)d_out;                   // [B,S*O] f32

    // workspace: wlast/carryW (in place) 8 MB + frag weights 128 KB
    float* wlast = (float*)d_ws;                              // [B][NC][WPB][H] f32
    short* bfrag = (short*)(wlast + (size_t)Bc * NCc * WPB * Hc);  // 64 KB
    short* cfrag = bfrag + 4096 * 8;                               // 64 KB

    prep_weights<<<32, 256, 0, stream>>>(bw, cw, bfrag, cfrag);
    pass1<<<dim3(NCc, Bc), 256, 0, stream>>>(x, bfrag, Adiag, wlast);
    carry2<<<64, 256, 0, stream>>>(Adiag, wlast);
    pass2<<<dim3(NCc, Bc), 256, 0, stream>>>(x, bfrag, cfrag, Adiag, wlast, out);
}